// Round 6
// baseline (249.512 us; speedup 1.0000x reference)
//
#include <hip/hip_runtime.h>
#include <math.h>

#define DIM    2048
#define BATCH  256
#define PN     56          // PATCH_NUM - MASK_NUM
#define CHUNK  128         // columns staged in LDS at a time
#define NCHUNK 4           // chunks per block
#define NQ     4           // column-quarters per batch row (DIM / QCOLS)
#define QCOLS  (CHUNK * NCHUNK)   // 512 cols per block
#define NBLK   (BATCH * NQ)       // 1024 blocks = exactly 4/CU
constexpr float KD_T = 4.0f;

// ---------------- reduction helpers (wave = 64) ----------------
__device__ __forceinline__ float wave_sum(float v) {
#pragma unroll
    for (int o = 32; o > 0; o >>= 1) v += __shfl_xor(v, o, 64);
    return v;
}
__device__ __forceinline__ float half_sum(float v) {   // reduce within 32-lane half
#pragma unroll
    for (int o = 16; o > 0; o >>= 1) v += __shfl_xor(v, o, 64);
    return v;
}
__device__ __forceinline__ double wave_sum_d(double v) {
#pragma unroll
    for (int o = 32; o > 0; o >>= 1) v += __shfl_xor(v, o, 64);
    return v;
}

// ---------------- fused bar + dil + dcl (single HBM pass over ebp) ---------
// Software-pipelined WITHOUT lambdas (R5's lambda array params decayed to
// pointers -> scratch spill, 146MB WRITE_SIZE). The chunk loop is fully
// unrolled; cur/nxt are constant-indexed register arrays; prefetch of chunk
// c+1 issues right after barrier 1 and overlaps pass B. 2 barriers/chunk.
// pdcl layout TRANSPOSED for coalesced finalize: [(p*BATCH + b)*NQ + q][4].
__global__ void __launch_bounds__(256, 4) fused_kernel(const float* __restrict__ ebg,
                                                       const float* __restrict__ ebp,
                                                       float* __restrict__ pdcl,
                                                       float* __restrict__ pdil)  // [NBLK][4]
{
    __shared__ float  ebp_s[PN * CHUNK];   // 28672 B
    __shared__ float4 redbar[4][32];       // 2048 B  (per-wave bar partials)
    __shared__ float  redl[4][4];

    const int t    = threadIdx.x;
    const int lane = t & 63;
    const int wv   = t >> 6;
    const int sub  = lane >> 5;            // half-wave id
    const int c32  = lane & 31;
    const int bid  = blockIdx.x;
    const int b    = bid >> 2;
    const int q    = bid & (NQ - 1);
    const float invT = 1.0f / KD_T;
    const float invP = 1.0f / PN;

    const size_t rowoff = (size_t)b * DIM + (size_t)q * QCOLS;
    const int prow0 = t >> 5;              // 0..7 : p-row offset for staging
    const int cc4   = (t & 31) * 4;
    const float* ebase = ebp + rowoff + cc4;

    float acc[7][4];                        // per-lane; row = wv*14 + 2*j + sub
#pragma unroll
    for (int j = 0; j < 7; ++j)
#pragma unroll
        for (int k = 0; k < 4; ++k) acc[j][k] = 0.f;

    float dss = 0.f, dts = 0.f, dt1 = 0.f, dt2 = 0.f;   // dil (threads t<128)

    float4 cur[7], nxt[7];
#pragma unroll
    for (int it = 0; it < 7; ++it)
        cur[it] = *(const float4*)(ebase + (size_t)(it * 8 + prow0) * (BATCH * DIM));

#pragma unroll
    for (int c = 0; c < NCHUNK; ++c) {
        const size_t cb = rowoff + (size_t)c * CHUNK;

        // ---- stage chunk c to LDS + per-wave bar partial ----
        float4 bp = {0.f, 0.f, 0.f, 0.f};
#pragma unroll
        for (int it = 0; it < 7; ++it) {
            *(float4*)(ebp_s + (it * 8 + prow0) * CHUNK + cc4) = cur[it];
            bp.x += cur[it].x; bp.y += cur[it].y;
            bp.z += cur[it].z; bp.w += cur[it].w;
        }
        bp.x += __shfl_xor(bp.x, 32, 64);
        bp.y += __shfl_xor(bp.y, 32, 64);
        bp.z += __shfl_xor(bp.z, 32, 64);
        bp.w += __shfl_xor(bp.w, 32, 64);
        if (lane < 32) redbar[wv][lane] = bp;
        __syncthreads();

        // ---- prefetch chunk c+1 (overlaps pass B below) ----
        if (c + 1 < NCHUNK) {
#pragma unroll
            for (int it = 0; it < 7; ++it)
                nxt[it] = *(const float4*)(ebase + (size_t)(c + 1) * CHUNK
                                           + (size_t)(it * 8 + prow0) * (BATCH * DIM));
        }

        // ---- bar for my 4 columns from the 4 wave partials ----
        float4 r0 = redbar[0][c32], r1 = redbar[1][c32],
               r2 = redbar[2][c32], r3 = redbar[3][c32];
        const float ms0 = (r0.x + r1.x + r2.x + r3.x) * invP;
        const float ms1 = (r0.y + r1.y + r2.y + r3.y) * invP;
        const float ms2 = (r0.z + r1.z + r2.z + r3.z) * invP;
        const float ms3 = (r0.w + r1.w + r2.w + r3.w) * invP;

        // ---- dil partials (threads 0..127, one column each) ----
        if (t < CHUNK) {
            const float* rb = (const float*)redbar;
            float bc = (rb[t] + rb[128 + t] + rb[256 + t] + rb[384 + t]) * invP;
            float g = ebg[cb + t];
            float s = g * invT, tv = bc * invT;
            float es = __expf(s), et = __expf(tv);
            float dd = tv - s;
            dss += es; dts += et;
            dt1 = fmaf(es, dd, dt1);
            dt2 = fmaf(et, dd, dt2);
        }

        // ---- pass B: half-wave per row, 14 rows per wave ----
        const float4 g4 = *(const float4*)(ebg + cb + c32 * 4);
        const float gs[4] = {g4.x, g4.y, g4.z, g4.w};
        const float msv[4] = {ms0, ms1, ms2, ms3};
#pragma unroll
        for (int j = 0; j < 7; ++j) {
            const int row = wv * 14 + 2 * j + sub;
            float4 e = *(const float4*)(ebp_s + row * CHUNK + c32 * 4);
            float es_[4] = {e.x, e.y, e.z, e.w};
#pragma unroll
            for (int k = 0; k < 4; ++k) {
                float dg = gs[k] - es_[k];
                float db = msv[k] - es_[k];
                float a  = dg * dg * invT;
                float cc2 = db * db * invT;
                float ea = __expf(a), ec = __expf(cc2);
                float d  = cc2 - a;
                acc[j][0] += ea;
                acc[j][1] += ec;
                acc[j][2] = fmaf(ea, d, acc[j][2]);
                acc[j][3] = fmaf(ec, d, acc[j][3]);
            }
        }
        __syncthreads();   // protect ebp_s/redbar before next chunk's staging

        if (c + 1 < NCHUNK) {
#pragma unroll
            for (int it = 0; it < 7; ++it) cur[it] = nxt[it];
        }
    }

    // ---- dcl partials: half-wave reductions, lanes 0 & 32 write ----
#pragma unroll
    for (int j = 0; j < 7; ++j) {
        float a0 = half_sum(acc[j][0]);
        float a1 = half_sum(acc[j][1]);
        float a2 = half_sum(acc[j][2]);
        float a3 = half_sum(acc[j][3]);
        if (c32 == 0) {
            const int row = wv * 14 + 2 * j + sub;
            float* qp = pdcl + (((size_t)row * BATCH + b) * NQ + q) * 4;
            qp[0] = a0; qp[1] = a1; qp[2] = a2; qp[3] = a3;
        }
    }
    // ---- dil block reduction (waves 2,3 contribute zeros) ----
    dss = wave_sum(dss); dts = wave_sum(dts);
    dt1 = wave_sum(dt1); dt2 = wave_sum(dt2);
    if (lane == 0) { redl[wv][0] = dss; redl[wv][1] = dts; redl[wv][2] = dt1; redl[wv][3] = dt2; }
    __syncthreads();
    if (t == 0) {
        float* qp = pdil + (size_t)bid * 4;
#pragma unroll
        for (int k = 0; k < 4; ++k)
            qp[k] = redl[0][k] + redl[1][k] + redl[2][k] + redl[3][k];
    }
}

// ---------------- finalize 1: per-(b,p) ratios, reduced per p-block --------
__global__ void __launch_bounds__(256) finalize1_kernel(const float* __restrict__ pdcl,
                                                        double* __restrict__ partial)
{
    __shared__ double sd[4];
    const int p = blockIdx.x, t = threadIdx.x, lane = t & 63, wv = t >> 6;
    const float* base = pdcl + ((size_t)p * BATCH + t) * NQ * 4;
    double A = 0.0, C = 0.0, T1 = 0.0, T2 = 0.0;
#pragma unroll
    for (int qq = 0; qq < NQ; ++qq) {
        float4 v = *(const float4*)(base + qq * 4);
        A += v.x; C += v.y; T1 += v.z; T2 += v.w;
    }
    double r = T2 / C - T1 / A;
    r = wave_sum_d(r);
    if (lane == 0) sd[wv] = r;
    __syncthreads();
    if (t == 0) partial[p] = sd[0] + sd[1] + sd[2] + sd[3];
}

// ---------------- finalize 2: combine p-partials + dil, emit outputs ------
__global__ void __launch_bounds__(256) finalize2_kernel(const double* __restrict__ partial,
                                                        const float* __restrict__ pdil,
                                                        float* __restrict__ out)
{
    __shared__ double sdc[4], sdl[4];
    const int t = threadIdx.x, lane = t & 63, wv = t >> 6;

    double vd = (t < PN) ? partial[t] : 0.0;

    const float* base = pdil + (size_t)t * NQ * 4;
    double ss = 0.0, ts = 0.0, u1 = 0.0, u2 = 0.0;
#pragma unroll
    for (int qq = 0; qq < NQ; ++qq) {
        float4 v = *(const float4*)(base + qq * 4);
        ss += v.x; ts += v.y; u1 += v.z; u2 += v.w;
    }
    double vl = u2 / ts - u1 / ss;

    vd = wave_sum_d(vd); vl = wave_sum_d(vl);
    if (lane == 0) { sdc[wv] = vd; sdl[wv] = vl; }
    __syncthreads();
    if (t == 0) {
        const double kT2 = (double)KD_T * KD_T;
        out[0] = (float)((sdl[0] + sdl[1] + sdl[2] + sdl[3]) * (kT2 / DIM));
        out[1] = (float)((sdc[0] + sdc[1] + sdc[2] + sdc[3]) * (kT2 / DIM / PN));
    }
}

extern "C" void kernel_launch(void* const* d_in, const int* in_sizes, int n_in,
                              void* d_out, int out_size, void* d_ws, size_t ws_size,
                              hipStream_t stream) {
    const float* ebg = (const float*)d_in[0];
    const float* ebp = (const float*)d_in[1];
    // labels (d_in[2]) unused by the forward computation

    float*  pdcl    = (float*)d_ws;                                   // PN*BATCH*NQ*4 floats = 896 KB
    float*  pdil    = pdcl + (size_t)PN * BATCH * NQ * 4;             // NBLK*4 floats = 16 KB
    double* partial = (double*)(pdil + (size_t)NBLK * 4);             // PN doubles

    fused_kernel<<<NBLK, 256, 0, stream>>>(ebg, ebp, pdcl, pdil);
    finalize1_kernel<<<PN, 256, 0, stream>>>(pdcl, partial);
    finalize2_kernel<<<1, 256, 0, stream>>>(partial, pdil, (float*)d_out);
}

// Round 7
// 246.393 us; speedup vs baseline: 1.0127x; 1.0127x over previous
//
#include <hip/hip_runtime.h>
#include <math.h>

#define DIM    2048
#define BATCH  256
#define PN     56          // PATCH_NUM - MASK_NUM
#define CHUNK  128         // columns staged in LDS at a time
#define NCHUNK 4           // chunks per block
#define NQ     4           // column-quarters per batch row (DIM / QCOLS)
#define QCOLS  (CHUNK * NCHUNK)   // 512 cols per block
#define NBLK   (BATCH * NQ)       // 1024 blocks = exactly 4/CU
#define BDIM   (BATCH * DIM)
constexpr float KD_T = 4.0f;

// ---------------- reduction helpers (wave = 64) ----------------
__device__ __forceinline__ float wave_sum(float v) {
#pragma unroll
    for (int o = 32; o > 0; o >>= 1) v += __shfl_xor(v, o, 64);
    return v;
}
__device__ __forceinline__ float half_sum(float v) {   // reduce within 32-lane half
#pragma unroll
    for (int o = 16; o > 0; o >>= 1) v += __shfl_xor(v, o, 64);
    return v;
}
__device__ __forceinline__ double wave_sum_d(double v) {
#pragma unroll
    for (int o = 32; o > 0; o >>= 1) v += __shfl_xor(v, o, 64);
    return v;
}

// load 7 float4 (rows it*8+prow0 of the chunk); ebase has rowoff+cc4+prow0*BDIM folded in
__device__ __forceinline__ void load_chunk7(const float* __restrict__ ebase,
                                            int c, float4 (&v)[7]) {
#pragma unroll
    for (int it = 0; it < 7; ++it)
        v[it] = *(const float4*)(ebase + (size_t)c * CHUNK + (size_t)it * 8 * BDIM);
}

// ---------------- fused bar + dil + dcl (single HBM pass over ebp) ---------
// R6 post-mortem: VGPR_Count=64=512/8 -> backend's memory-bound heuristic
// targeted 8 waves/EU and spilled the double-buffer (146MB scratch writes).
// amdgpu_waves_per_eu(4,4) pins the range: 128-VGPR budget, no spill.
// Software-pipelined: chunk c+1's loads issue after barrier 1, overlapping
// pass B. 2 barriers/chunk. Reference-to-array params avoid pointer decay.
// pdcl layout TRANSPOSED for coalesced finalize: [(p*BATCH + b)*NQ + q][4].
__global__ __attribute__((amdgpu_waves_per_eu(4, 4))) __launch_bounds__(256)
void fused_kernel(const float* __restrict__ ebg,
                  const float* __restrict__ ebp,
                  float* __restrict__ pdcl,
                  float* __restrict__ pdil)  // [NBLK][4]
{
    __shared__ float  ebp_s[PN * CHUNK];   // 28672 B
    __shared__ float4 redbar[4][32];       // 2048 B  (per-wave bar partials)
    __shared__ float  redl[4][4];

    const int t    = threadIdx.x;
    const int lane = t & 63;
    const int wv   = t >> 6;
    const int sub  = lane >> 5;            // half-wave id
    const int c32  = lane & 31;
    const int bid  = blockIdx.x;
    const int b    = bid >> 2;
    const int q    = bid & (NQ - 1);
    const float invT = 1.0f / KD_T;
    const float invP = 1.0f / PN;

    const size_t rowoff = (size_t)b * DIM + (size_t)q * QCOLS;
    const int prow0 = t >> 5;              // 0..7 : p-row offset for staging
    const int cc4   = (t & 31) * 4;
    const float* ebase = ebp + rowoff + cc4 + (size_t)prow0 * BDIM;

    float acc[7][4];                        // per-lane; row = wv*14 + 2*j + sub
#pragma unroll
    for (int j = 0; j < 7; ++j)
#pragma unroll
        for (int k = 0; k < 4; ++k) acc[j][k] = 0.f;

    float dss = 0.f, dts = 0.f, dt1 = 0.f, dt2 = 0.f;   // dil (threads t<128)

    float4 cur[7], nxt[7];
    load_chunk7(ebase, 0, cur);

#pragma unroll
    for (int c = 0; c < NCHUNK; ++c) {
        const size_t cb = rowoff + (size_t)c * CHUNK;

        // ---- stage chunk c to LDS + per-wave bar partial ----
        float4 bp = {0.f, 0.f, 0.f, 0.f};
#pragma unroll
        for (int it = 0; it < 7; ++it) {
            *(float4*)(ebp_s + (it * 8 + prow0) * CHUNK + cc4) = cur[it];
            bp.x += cur[it].x; bp.y += cur[it].y;
            bp.z += cur[it].z; bp.w += cur[it].w;
        }
        bp.x += __shfl_xor(bp.x, 32, 64);
        bp.y += __shfl_xor(bp.y, 32, 64);
        bp.z += __shfl_xor(bp.z, 32, 64);
        bp.w += __shfl_xor(bp.w, 32, 64);
        if (lane < 32) redbar[wv][lane] = bp;
        __syncthreads();

        // ---- prefetch chunk c+1 (overlaps pass B below) ----
        if (c + 1 < NCHUNK) load_chunk7(ebase, c + 1, nxt);

        // ---- bar for my 4 columns from the 4 wave partials ----
        float4 r0 = redbar[0][c32], r1 = redbar[1][c32],
               r2 = redbar[2][c32], r3 = redbar[3][c32];
        const float msv[4] = {(r0.x + r1.x + r2.x + r3.x) * invP,
                              (r0.y + r1.y + r2.y + r3.y) * invP,
                              (r0.z + r1.z + r2.z + r3.z) * invP,
                              (r0.w + r1.w + r2.w + r3.w) * invP};

        // ---- dil partials (threads 0..127, one column each) ----
        if (t < CHUNK) {
            const float* rb = (const float*)redbar;
            float bc = (rb[t] + rb[128 + t] + rb[256 + t] + rb[384 + t]) * invP;
            float g = ebg[cb + t];
            float s = g * invT, tv = bc * invT;
            float es = __expf(s), et = __expf(tv);
            float dd = tv - s;
            dss += es; dts += et;
            dt1 = fmaf(es, dd, dt1);
            dt2 = fmaf(et, dd, dt2);
        }

        // ---- pass B: half-wave per row, 14 rows per wave ----
        const float4 g4 = *(const float4*)(ebg + cb + c32 * 4);
        const float gs[4] = {g4.x, g4.y, g4.z, g4.w};
#pragma unroll
        for (int j = 0; j < 7; ++j) {
            const int row = wv * 14 + 2 * j + sub;
            float4 e = *(const float4*)(ebp_s + row * CHUNK + c32 * 4);
            float es_[4] = {e.x, e.y, e.z, e.w};
#pragma unroll
            for (int k = 0; k < 4; ++k) {
                float dg = gs[k] - es_[k];
                float db = msv[k] - es_[k];
                float a  = dg * dg * invT;
                float cc2 = db * db * invT;
                float ea = __expf(a), ec = __expf(cc2);
                float d  = cc2 - a;
                acc[j][0] += ea;
                acc[j][1] += ec;
                acc[j][2] = fmaf(ea, d, acc[j][2]);
                acc[j][3] = fmaf(ec, d, acc[j][3]);
            }
        }
        __syncthreads();   // protect ebp_s/redbar before next chunk's staging

        if (c + 1 < NCHUNK) {
#pragma unroll
            for (int it = 0; it < 7; ++it) cur[it] = nxt[it];
        }
    }

    // ---- dcl partials: half-wave reductions, lanes 0 & 32 write ----
#pragma unroll
    for (int j = 0; j < 7; ++j) {
        float a0 = half_sum(acc[j][0]);
        float a1 = half_sum(acc[j][1]);
        float a2 = half_sum(acc[j][2]);
        float a3 = half_sum(acc[j][3]);
        if (c32 == 0) {
            const int row = wv * 14 + 2 * j + sub;
            float* qp = pdcl + (((size_t)row * BATCH + b) * NQ + q) * 4;
            qp[0] = a0; qp[1] = a1; qp[2] = a2; qp[3] = a3;
        }
    }
    // ---- dil block reduction (waves 2,3 contribute zeros) ----
    dss = wave_sum(dss); dts = wave_sum(dts);
    dt1 = wave_sum(dt1); dt2 = wave_sum(dt2);
    if (lane == 0) { redl[wv][0] = dss; redl[wv][1] = dts; redl[wv][2] = dt1; redl[wv][3] = dt2; }
    __syncthreads();
    if (t == 0) {
        float* qp = pdil + (size_t)bid * 4;
#pragma unroll
        for (int k = 0; k < 4; ++k)
            qp[k] = redl[0][k] + redl[1][k] + redl[2][k] + redl[3][k];
    }
}

// ---------------- finalize 1: per-(b,p) ratios, reduced per p-block --------
__global__ void __launch_bounds__(256) finalize1_kernel(const float* __restrict__ pdcl,
                                                        double* __restrict__ partial)
{
    __shared__ double sd[4];
    const int p = blockIdx.x, t = threadIdx.x, lane = t & 63, wv = t >> 6;
    const float* base = pdcl + ((size_t)p * BATCH + t) * NQ * 4;
    double A = 0.0, C = 0.0, T1 = 0.0, T2 = 0.0;
#pragma unroll
    for (int qq = 0; qq < NQ; ++qq) {
        float4 v = *(const float4*)(base + qq * 4);
        A += v.x; C += v.y; T1 += v.z; T2 += v.w;
    }
    double r = T2 / C - T1 / A;
    r = wave_sum_d(r);
    if (lane == 0) sd[wv] = r;
    __syncthreads();
    if (t == 0) partial[p] = sd[0] + sd[1] + sd[2] + sd[3];
}

// ---------------- finalize 2: combine p-partials + dil, emit outputs ------
__global__ void __launch_bounds__(256) finalize2_kernel(const double* __restrict__ partial,
                                                        const float* __restrict__ pdil,
                                                        float* __restrict__ out)
{
    __shared__ double sdc[4], sdl[4];
    const int t = threadIdx.x, lane = t & 63, wv = t >> 6;

    double vd = (t < PN) ? partial[t] : 0.0;

    const float* base = pdil + (size_t)t * NQ * 4;
    double ss = 0.0, ts = 0.0, u1 = 0.0, u2 = 0.0;
#pragma unroll
    for (int qq = 0; qq < NQ; ++qq) {
        float4 v = *(const float4*)(base + qq * 4);
        ss += v.x; ts += v.y; u1 += v.z; u2 += v.w;
    }
    double vl = u2 / ts - u1 / ss;

    vd = wave_sum_d(vd); vl = wave_sum_d(vl);
    if (lane == 0) { sdc[wv] = vd; sdl[wv] = vl; }
    __syncthreads();
    if (t == 0) {
        const double kT2 = (double)KD_T * KD_T;
        out[0] = (float)((sdl[0] + sdl[1] + sdl[2] + sdl[3]) * (kT2 / DIM));
        out[1] = (float)((sdc[0] + sdc[1] + sdc[2] + sdc[3]) * (kT2 / DIM / PN));
    }
}

extern "C" void kernel_launch(void* const* d_in, const int* in_sizes, int n_in,
                              void* d_out, int out_size, void* d_ws, size_t ws_size,
                              hipStream_t stream) {
    const float* ebg = (const float*)d_in[0];
    const float* ebp = (const float*)d_in[1];
    // labels (d_in[2]) unused by the forward computation

    float*  pdcl    = (float*)d_ws;                                   // PN*BATCH*NQ*4 floats = 896 KB
    float*  pdil    = pdcl + (size_t)PN * BATCH * NQ * 4;             // NBLK*4 floats = 16 KB
    double* partial = (double*)(pdil + (size_t)NBLK * 4);             // PN doubles

    fused_kernel<<<NBLK, 256, 0, stream>>>(ebg, ebp, pdcl, pdil);
    finalize1_kernel<<<PN, 256, 0, stream>>>(pdcl, partial);
    finalize2_kernel<<<1, 256, 0, stream>>>(partial, pdil, (float*)d_out);
}

// Round 8
// 192.963 us; speedup vs baseline: 1.2931x; 1.2769x over previous
//
#include <hip/hip_runtime.h>
#include <math.h>

#define DIM    2048
#define BATCH  256
#define PN     56          // PATCH_NUM - MASK_NUM
#define CHUNK  64          // columns staged in LDS at a time
#define NCHUNK 4           // chunks per block
#define NQ     8           // column-slices per batch row
#define QCOLS  (CHUNK * NCHUNK)   // 256 cols per block
#define NBLK   (BATCH * NQ)       // 2048 blocks = 8/CU -> 32 waves/CU
#define BDIM   (BATCH * DIM)
constexpr float KD_T = 4.0f;

// ---------------- reduction helpers ----------------
__device__ __forceinline__ float wave_sum(float v) {        // 64 lanes
#pragma unroll
    for (int o = 32; o > 0; o >>= 1) v += __shfl_xor(v, o, 64);
    return v;
}
__device__ __forceinline__ float quarter_sum(float v) {     // 16-lane group
#pragma unroll
    for (int o = 8; o > 0; o >>= 1) v += __shfl_xor(v, o, 64);
    return v;
}
__device__ __forceinline__ double wave_sum_d(double v) {
#pragma unroll
    for (int o = 32; o > 0; o >>= 1) v += __shfl_xor(v, o, 64);
    return v;
}

// ---------------- fused bar + dil + dcl (single HBM pass over ebp) ---------
// R5-R7 post-mortem: the backend pins this kernel at 64 VGPR (8 waves/EU
// heuristic); any register double-buffer spills to scratch (146MB writes).
// So: NO prefetch registers. Latency hiding comes from occupancy instead:
// CHUNK=64 -> LDS 15.4KB, grid 2048 -> 8 blocks/CU = 32 waves/CU (100%).
// Staging: thread t -> row it*16 + (t>>4), float4-col t&15. Wave-uniform
// branches only. Pass B: quarter-wave per p-row, rows j*16 + wv*4 + qw.
// pdcl layout TRANSPOSED for coalesced finalize: [(p*BATCH + b)*NQ + q][4].
__global__ void __launch_bounds__(256) fused_kernel(const float* __restrict__ ebg,
                                                    const float* __restrict__ ebp,
                                                    float* __restrict__ pdcl,
                                                    float* __restrict__ pdil)  // [NBLK][4]
{
    __shared__ float ebp_s[PN * CHUNK];   // 14336 B
    __shared__ float redbar[4][CHUNK];    // 1024 B  (per-wave column partials)

    const int t    = threadIdx.x;
    const int lane = t & 63;
    const int wv   = t >> 6;
    const int qw   = lane >> 4;            // quarter-wave id 0..3
    const int c16  = lane & 15;            // float4-col within chunk
    const int bid  = blockIdx.x;
    const int b    = bid >> 3;
    const int q    = bid & (NQ - 1);
    const float invT = 1.0f / KD_T;
    const float invP = 1.0f / PN;

    const size_t rowoff = (size_t)b * DIM + (size_t)q * QCOLS;
    const int prow = t >> 4;               // 0..15 staging row offset
    const int col4 = t & 15;
    const float* ebase = ebp + rowoff + (size_t)prow * BDIM + col4 * 4;

    float acc[4][4];                        // quarter-wave rows j*16+wv*4+qw
#pragma unroll
    for (int j = 0; j < 4; ++j)
#pragma unroll
        for (int k = 0; k < 4; ++k) acc[j][k] = 0.f;

    float dss = 0.f, dts = 0.f, dt1 = 0.f, dt2 = 0.f;   // dil (wave 0 only)

#pragma unroll
    for (int c = 0; c < NCHUNK; ++c) {
        const size_t cb = rowoff + (size_t)c * CHUNK;

        // ---- stage chunk c (rows prow, prow+16, prow+32 [,prow+48]) ----
        float4 v0 = *(const float4*)(ebase + c * CHUNK);
        float4 v1 = *(const float4*)(ebase + c * CHUNK + (size_t)16 * BDIM);
        float4 v2 = *(const float4*)(ebase + c * CHUNK + (size_t)32 * BDIM);
        *(float4*)(ebp_s + prow * CHUNK + col4 * 4)        = v0;
        *(float4*)(ebp_s + (prow + 16) * CHUNK + col4 * 4) = v1;
        *(float4*)(ebp_s + (prow + 32) * CHUNK + col4 * 4) = v2;
        float4 bsum;
        bsum.x = v0.x + v1.x + v2.x; bsum.y = v0.y + v1.y + v2.y;
        bsum.z = v0.z + v1.z + v2.z; bsum.w = v0.w + v1.w + v2.w;
        if (prow < 8) {                    // wave-uniform (waves 0,1 only)
            float4 v3 = *(const float4*)(ebase + c * CHUNK + (size_t)48 * BDIM);
            *(float4*)(ebp_s + (prow + 48) * CHUNK + col4 * 4) = v3;
            bsum.x += v3.x; bsum.y += v3.y; bsum.z += v3.z; bsum.w += v3.w;
        }
        // combine the wave's 4 prow-groups (lanes xor 16, xor 32 share c16)
        bsum.x += __shfl_xor(bsum.x, 16, 64); bsum.x += __shfl_xor(bsum.x, 32, 64);
        bsum.y += __shfl_xor(bsum.y, 16, 64); bsum.y += __shfl_xor(bsum.y, 32, 64);
        bsum.z += __shfl_xor(bsum.z, 16, 64); bsum.z += __shfl_xor(bsum.z, 32, 64);
        bsum.w += __shfl_xor(bsum.w, 16, 64); bsum.w += __shfl_xor(bsum.w, 32, 64);
        if (lane < 16) *(float4*)(&redbar[wv][lane * 4]) = bsum;
        __syncthreads();

        // ---- dil partials (wave 0, one column each) ----
        if (t < CHUNK) {
            float bc = (redbar[0][t] + redbar[1][t] + redbar[2][t] + redbar[3][t]) * invP;
            float g = ebg[cb + t];
            float s = g * invT, tv = bc * invT;
            float es = __expf(s), et = __expf(tv);
            float dd = tv - s;
            dss += es; dts += et;
            dt1 = fmaf(es, dd, dt1);
            dt2 = fmaf(et, dd, dt2);
        }

        // ---- bar + ebg for my 4 columns ----
        float4 r0 = *(const float4*)(&redbar[0][c16 * 4]);
        float4 r1 = *(const float4*)(&redbar[1][c16 * 4]);
        float4 r2 = *(const float4*)(&redbar[2][c16 * 4]);
        float4 r3 = *(const float4*)(&redbar[3][c16 * 4]);
        const float msv[4] = {(r0.x + r1.x + r2.x + r3.x) * invP,
                              (r0.y + r1.y + r2.y + r3.y) * invP,
                              (r0.z + r1.z + r2.z + r3.z) * invP,
                              (r0.w + r1.w + r2.w + r3.w) * invP};
        const float4 g4 = *(const float4*)(ebg + cb + c16 * 4);
        const float gs[4] = {g4.x, g4.y, g4.z, g4.w};

        // ---- pass B: quarter-wave per row ----
#pragma unroll
        for (int j = 0; j < 4; ++j) {
            if (j < 3 || wv < 2) {         // wave-uniform (rows 48..55: waves 0,1)
                const int row = j * 16 + wv * 4 + qw;
                float4 e = *(const float4*)(ebp_s + row * CHUNK + c16 * 4);
                float es_[4] = {e.x, e.y, e.z, e.w};
#pragma unroll
                for (int k = 0; k < 4; ++k) {
                    float dg = gs[k] - es_[k];
                    float db = msv[k] - es_[k];
                    float a   = dg * dg * invT;
                    float cc2 = db * db * invT;
                    float ea = __expf(a), ec = __expf(cc2);
                    float d  = cc2 - a;
                    acc[j][0] += ea;
                    acc[j][1] += ec;
                    acc[j][2] = fmaf(ea, d, acc[j][2]);
                    acc[j][3] = fmaf(ec, d, acc[j][3]);
                }
            }
        }
        __syncthreads();   // protect ebp_s/redbar before next chunk's staging
    }

    // ---- dcl partials: quarter-wave reductions, c16==0 lanes write ----
#pragma unroll
    for (int j = 0; j < 4; ++j) {
        if (j < 3 || wv < 2) {
            float a0 = quarter_sum(acc[j][0]);
            float a1 = quarter_sum(acc[j][1]);
            float a2 = quarter_sum(acc[j][2]);
            float a3 = quarter_sum(acc[j][3]);
            if (c16 == 0) {
                const int row = j * 16 + wv * 4 + qw;
                float* qp = pdcl + (((size_t)row * BATCH + b) * NQ + q) * 4;
                qp[0] = a0; qp[1] = a1; qp[2] = a2; qp[3] = a3;
            }
        }
    }
    // ---- dil: only wave 0 is nonzero; reduce and write ----
    dss = wave_sum(dss); dts = wave_sum(dts);
    dt1 = wave_sum(dt1); dt2 = wave_sum(dt2);
    if (t == 0) {
        float* qp = pdil + (size_t)bid * 4;
        qp[0] = dss; qp[1] = dts; qp[2] = dt1; qp[3] = dt2;
    }
}

// ---------------- finalize 1: per-(b,p) ratios, reduced per p-block --------
__global__ void __launch_bounds__(256) finalize1_kernel(const float* __restrict__ pdcl,
                                                        double* __restrict__ partial)
{
    __shared__ double sd[4];
    const int p = blockIdx.x, t = threadIdx.x, lane = t & 63, wv = t >> 6;
    const float* base = pdcl + ((size_t)p * BATCH + t) * NQ * 4;
    double A = 0.0, C = 0.0, T1 = 0.0, T2 = 0.0;
#pragma unroll
    for (int qq = 0; qq < NQ; ++qq) {
        float4 v = *(const float4*)(base + qq * 4);
        A += v.x; C += v.y; T1 += v.z; T2 += v.w;
    }
    double r = T2 / C - T1 / A;
    r = wave_sum_d(r);
    if (lane == 0) sd[wv] = r;
    __syncthreads();
    if (t == 0) partial[p] = sd[0] + sd[1] + sd[2] + sd[3];
}

// ---------------- finalize 2: combine p-partials + dil, emit outputs ------
__global__ void __launch_bounds__(256) finalize2_kernel(const double* __restrict__ partial,
                                                        const float* __restrict__ pdil,
                                                        float* __restrict__ out)
{
    __shared__ double sdc[4], sdl[4];
    const int t = threadIdx.x, lane = t & 63, wv = t >> 6;

    double vd = (t < PN) ? partial[t] : 0.0;

    // dil: thread t owns batch row b=t; combine NQ slice-sums then ratio
    const float* base = pdil + (size_t)t * NQ * 4;
    double ss = 0.0, ts = 0.0, u1 = 0.0, u2 = 0.0;
#pragma unroll
    for (int qq = 0; qq < NQ; ++qq) {
        float4 v = *(const float4*)(base + qq * 4);
        ss += v.x; ts += v.y; u1 += v.z; u2 += v.w;
    }
    double vl = u2 / ts - u1 / ss;

    vd = wave_sum_d(vd); vl = wave_sum_d(vl);
    if (lane == 0) { sdc[wv] = vd; sdl[wv] = vl; }
    __syncthreads();
    if (t == 0) {
        const double kT2 = (double)KD_T * KD_T;
        out[0] = (float)((sdl[0] + sdl[1] + sdl[2] + sdl[3]) * (kT2 / DIM));
        out[1] = (float)((sdc[0] + sdc[1] + sdc[2] + sdc[3]) * (kT2 / DIM / PN));
    }
}

extern "C" void kernel_launch(void* const* d_in, const int* in_sizes, int n_in,
                              void* d_out, int out_size, void* d_ws, size_t ws_size,
                              hipStream_t stream) {
    const float* ebg = (const float*)d_in[0];
    const float* ebp = (const float*)d_in[1];
    // labels (d_in[2]) unused by the forward computation

    float*  pdcl    = (float*)d_ws;                                   // PN*BATCH*NQ*4 floats = 1.75 MB
    float*  pdil    = pdcl + (size_t)PN * BATCH * NQ * 4;             // NBLK*4 floats = 32 KB
    double* partial = (double*)(pdil + (size_t)NBLK * 4);             // PN doubles

    fused_kernel<<<NBLK, 256, 0, stream>>>(ebg, ebp, pdcl, pdil);
    finalize1_kernel<<<PN, 256, 0, stream>>>(pdcl, partial);
    finalize2_kernel<<<1, 256, 0, stream>>>(partial, pdil, (float*)d_out);
}